// Round 4
// baseline (410.580 us; speedup 1.0000x reference)
//
#include <hip/hip_runtime.h>

#define DEV __device__ __forceinline__

typedef _Float16 half8  __attribute__((ext_vector_type(8)));
typedef _Float16 half4h __attribute__((ext_vector_type(4)));
typedef float    f32x4  __attribute__((ext_vector_type(4)));

static constexpr int Bb = 8;
static constexpr int Ff = 16;
static constexpr int Pp = 196;
static constexpr int Dd = 768;
static constexpr int Hh = 12;
static constexpr int HD = 64;
static constexpr int Nn = 3136;    // F*P tokens per batch
static constexpr int NC = 392;     // Nn/8 token chunks per batch

#define MFMA(a, b, c) __builtin_amdgcn_mfma_f32_16x16x32_f16(a, b, c, 0, 0, 0)

DEV void gll16(const _Float16* g, _Float16* l) {
  __builtin_amdgcn_global_load_lds(
      (__attribute__((address_space(1))) void*)(g),
      (__attribute__((address_space(3))) void*)(l), 16, 0, 0);
}

// LDS-only fence: wait DS ops, compiler memory barrier (vmcnt stays in flight).
DEV void lds_fence() { asm volatile("s_waitcnt lgkmcnt(0)" ::: "memory"); }

// ---------------------------------------------------------------- convert
__global__ __launch_bounds__(256) void cvt_all(const float* __restrict__ x,
                                               const float* __restrict__ wq,
                                               const float* __restrict__ wp,
                                               _Float16* __restrict__ xh,
                                               _Float16* __restrict__ wqh,
                                               _Float16* __restrict__ wph) {
  const int NX = 4816896, NQ = 442368;  // in f32x4 units
  int i = blockIdx.x * 256 + threadIdx.x;
  const float* s;
  _Float16* d;
  int j;
  if (i < NX) { s = x; d = xh; j = i; }
  else if (i < NX + NQ) { s = wq; d = wqh; j = i - NX; }
  else { s = wp; d = wph; j = i - NX - NQ; }
  f32x4 v = ((const f32x4*)s)[j];
  half4h h;
  h.x = (_Float16)v.x; h.y = (_Float16)v.y;
  h.z = (_Float16)v.z; h.w = (_Float16)v.w;
  ((half4h*)d)[j] = h;
}

// ---------------------------------------------------------------- QKV GEMM
// One mode (Q/K/V) per launch: C[token][e] = sum_d X[token][d]*W[e][d],
// M=25088, N=768, K=768. 128x128 tile, BK=64 (32 MFMA per barrier pair).
// 8-chunk XOR swizzle: stored chunk cs at row holds global chunk cs^(row&7).
// mode 0: Q8 (scaled by 0.125), 1: K8, 2: V8 (transposed layout).
__global__ __launch_bounds__(256) void gemm_qkv(const _Float16* __restrict__ X,
                                                const _Float16* __restrict__ W,
                                                _Float16* __restrict__ Q8,
                                                _Float16* __restrict__ K8,
                                                _Float16* __restrict__ V8,
                                                const int mode) {
  __shared__ __align__(16) _Float16 smem[128 * 132];  // staging 32KB / C-tile 33KB
  _Float16* As = smem;              // [128 rows][8 chunks][8]
  _Float16* Bs = smem + 128 * 64;
  const int tid = threadIdx.x;
  const int lane = tid & 63, wid = tid >> 6;
  const int l15 = lane & 15, quad = lane >> 4;
  const int row0 = blockIdx.y * 128;
  const int e0 = blockIdx.x * 128;
  const int wm = (wid >> 1) * 64, wn = (wid & 1) * 64;

  const _Float16* Ag = X + (size_t)row0 * Dd;
  const _Float16* Bg = W + (size_t)e0 * Dd;

  f32x4 acc[4][4];
#pragma unroll
  for (int i = 0; i < 4; ++i)
#pragma unroll
    for (int j = 0; j < 4; ++j) acc[i][j] = (f32x4)0.0f;

  // staging slots: slot = i*256+tid; row=slot>>3, cs=slot&7, g=cs^(row&7)
  int srow[4], soff[4];
#pragma unroll
  for (int i = 0; i < 4; ++i) {
    const int slot = i * 256 + tid;
    srow[i] = slot >> 3;
    soff[i] = ((slot & 7) ^ (srow[i] & 7)) * 8;
  }

  for (int kt = 0; kt < 12; ++kt) {
    const int k0 = kt * 64;
    __syncthreads();
#pragma unroll
    for (int i = 0; i < 4; ++i) {
      gll16(Ag + (size_t)srow[i] * Dd + k0 + soff[i], As + (i * 256 + tid) * 8);
      gll16(Bg + (size_t)srow[i] * Dd + k0 + soff[i], Bs + (i * 256 + tid) * 8);
    }
    __syncthreads();
#pragma unroll
    for (int kh = 0; kh < 2; ++kh) {
      half8 af[4], bf[4];
      const int sc = ((kh * 4 + quad) ^ (l15 & 7)) * 8;
#pragma unroll
      for (int t = 0; t < 4; ++t) {
        af[t] = *(const half8*)(As + (wm + t * 16 + l15) * 64 + sc);
        bf[t] = *(const half8*)(Bs + (wn + t * 16 + l15) * 64 + sc);
      }
#pragma unroll
      for (int i = 0; i < 4; ++i)
#pragma unroll
        for (int j = 0; j < 4; ++j) acc[i][j] = MFMA(af[i], bf[j], acc[i][j]);
    }
  }

  __syncthreads();
  if (mode == 2) {
    // transpose to LDS Ct[e_local][tok], stride 132
#pragma unroll
    for (int i = 0; i < 4; ++i)
#pragma unroll
      for (int j = 0; j < 4; ++j) {
        const int m = wm + i * 16 + quad * 4;
        const int n = wn + j * 16 + l15;
        half4h hv;
        hv.x = (_Float16)acc[i][j].x; hv.y = (_Float16)acc[i][j].y;
        hv.z = (_Float16)acc[i][j].z; hv.w = (_Float16)acc[i][j].w;
        *(half4h*)(smem + n * 132 + m) = hv;
      }
    __syncthreads();
    for (int c = tid; c < 2048; c += 256) {
      const int ncl = c >> 7, el = c & 127;
      const int e = e0 + el;
      const int h = e >> 6, d = e & 63;
      const int r = row0 + ncl * 8;
      const int b = r / Nn, n = r % Nn;
      const half4h lo = *(const half4h*)(smem + el * 132 + ncl * 8);
      const half4h hi = *(const half4h*)(smem + el * 132 + ncl * 8 + 4);
      half8 v;
#pragma unroll
      for (int z = 0; z < 4; ++z) { v[z] = lo[z]; v[4 + z] = hi[z]; }
      *(half8*)(V8 + (((size_t)(b * Hh + h) * NC + (n >> 3)) * 64 + d) * 8) = v;
    }
  } else {
    _Float16* Ob = (mode == 0) ? Q8 : K8;
    const float qs = (mode == 0) ? 0.125f : 1.0f;  // fold softmax scale into Q
#pragma unroll
    for (int i = 0; i < 4; ++i)
#pragma unroll
      for (int j = 0; j < 4; ++j) {
        const int n = wn + j * 16 + l15;
#pragma unroll
        for (int r = 0; r < 4; ++r) {
          const int m = wm + i * 16 + quad * 4 + r;
          smem[m * 132 + n] = (_Float16)(acc[i][j][r] * qs);
        }
      }
    __syncthreads();
    for (int c = tid; c < 2048; c += 256) {
      const int ec = c >> 7, m = c & 127;
      const int r = row0 + m;
      const int b = r / Nn, n = r % Nn;
      const int e = e0 + ec * 8;
      const int h = e >> 6, dc = (e >> 3) & 7;
      const half4h lo = *(const half4h*)(smem + m * 132 + ec * 8);
      const half4h hi = *(const half4h*)(smem + m * 132 + ec * 8 + 4);
      half8 v;
#pragma unroll
      for (int z = 0; z < 4; ++z) { v[z] = lo[z]; v[4 + z] = hi[z]; }
      *(half8*)(Ob + (((size_t)(b * Hh + h) * 8 + dc) * Nn + n) * 8) = v;
    }
  }
}

// ---------------------------------------------------------------- proj GEMM
__global__ __launch_bounds__(256) void gemm_proj(const _Float16* __restrict__ Wbuf,
                                                 const _Float16* __restrict__ Wp,
                                                 const float* __restrict__ bias,
                                                 float* __restrict__ Out) {
  __shared__ __align__(16) _Float16 smem[128 * 128];  // 32 KB staging
  _Float16* As = smem;
  _Float16* Bs = smem + 128 * 64;
  const int tid = threadIdx.x;
  const int lane = tid & 63, wid = tid >> 6;
  const int l15 = lane & 15, quad = lane >> 4;
  const int row0 = blockIdx.y * 128;
  const int e0 = blockIdx.x * 128;
  const int wm = (wid >> 1) * 64, wn = (wid & 1) * 64;

  const _Float16* Ag = Wbuf + (size_t)row0 * Dd;
  const _Float16* Bg = Wp + (size_t)e0 * Dd;

  f32x4 acc[4][4];
#pragma unroll
  for (int i = 0; i < 4; ++i)
#pragma unroll
    for (int j = 0; j < 4; ++j) acc[i][j] = (f32x4)0.0f;

  int srow[4], soff[4];
#pragma unroll
  for (int i = 0; i < 4; ++i) {
    const int slot = i * 256 + tid;
    srow[i] = slot >> 3;
    soff[i] = ((slot & 7) ^ (srow[i] & 7)) * 8;
  }

  for (int kt = 0; kt < 12; ++kt) {
    const int k0 = kt * 64;
    __syncthreads();
#pragma unroll
    for (int i = 0; i < 4; ++i) {
      gll16(Ag + (size_t)srow[i] * Dd + k0 + soff[i], As + (i * 256 + tid) * 8);
      gll16(Bg + (size_t)srow[i] * Dd + k0 + soff[i], Bs + (i * 256 + tid) * 8);
    }
    __syncthreads();
#pragma unroll
    for (int kh = 0; kh < 2; ++kh) {
      half8 af[4], bf[4];
      const int sc = ((kh * 4 + quad) ^ (l15 & 7)) * 8;
#pragma unroll
      for (int t = 0; t < 4; ++t) {
        af[t] = *(const half8*)(As + (wm + t * 16 + l15) * 64 + sc);
        bf[t] = *(const half8*)(Bs + (wn + t * 16 + l15) * 64 + sc);
      }
#pragma unroll
      for (int i = 0; i < 4; ++i)
#pragma unroll
        for (int j = 0; j < 4; ++j) acc[i][j] = MFMA(af[i], bf[j], acc[i][j]);
    }
  }

#pragma unroll
  for (int j = 0; j < 4; ++j) {
    const int e = e0 + wn + j * 16 + l15;
    const float bj = bias[e];
#pragma unroll
    for (int i = 0; i < 4; ++i) {
      const int rb = row0 + wm + i * 16 + quad * 4;
#pragma unroll
      for (int r = 0; r < 4; ++r)
        Out[(size_t)(rb + r) * Dd + e] = acc[i][j][r] + bj;
    }
  }
}

// ------------------------------------------------------------ spatial attn
// Transposed scheme: St = K·Q^T (softmax sum = in-lane + 2 shuffles, no max
// pass; Q pre-scaled by 0.125), P^T row=q in LDS feeds PV's B-operand, V as
// A-operand -> O^T rows are 4 consecutive d -> packed 8B stores.
__global__ __launch_bounds__(256) void attn_spatial(const _Float16* __restrict__ Q8,
                                                    const _Float16* __restrict__ K8,
                                                    const _Float16* __restrict__ V8,
                                                    _Float16* __restrict__ Wbuf) {
  __shared__ __align__(16) _Float16 Vs[64 * 216];       // 27648 B
  __shared__ __align__(16) _Float16 Plds[4][16 * 232];  // 29696 B
  const int tid = threadIdx.x;
  const int lane = tid & 63, wid = tid >> 6;
  const int l15 = lane & 15, quad = lane >> 4;
  const int gid = blockIdx.x;
  const int h = gid % 6, f = (gid / 6) % Ff, b = gid / 96;
  const size_t bh = (size_t)b * Hh + h;
  const int g0 = f * Pp;
  const int off = g0 & 7;
  const int nc0 = g0 >> 3;
  const _Float16* Qp = Q8 + bh * 8 * (size_t)Nn * 8;
  const _Float16* Kp = K8 + bh * 8 * (size_t)Nn * 8;

  for (int c = tid; c < 26 * 64; c += 256) {
    const int d = c & 63, ncl = c >> 6;
    const half8 v = *(const half8*)(V8 + ((bh * NC + nc0 + ncl) * 64 + d) * 8);
    _Float16* dst = Vs + d * 216 + (8 - off) + ncl * 8;
    half4h lo, hi;
#pragma unroll
    for (int z = 0; z < 4; ++z) { lo[z] = v[z]; hi[z] = v[4 + z]; }
    *(half4h*)dst = lo;
    *(half4h*)(dst + 4) = hi;
  }
  _Float16* Pw = &Plds[wid][0];
  if (quad < 3) {  // zero P cols 208..231
    half8 z8;
#pragma unroll
    for (int z = 0; z < 8; ++z) z8[z] = (_Float16)0.0f;
    *(half8*)(Pw + l15 * 232 + 208 + quad * 8) = z8;
  }
  __syncthreads();

  half8 h8z;
#pragma unroll
  for (int z = 0; z < 8; ++z) h8z[z] = (_Float16)0.0f;

  for (int it = 0; it < 4; ++it) {
    const int qi = wid + it * 4;
    if (qi > 12) continue;
    const int qr = qi * 16 + l15;
    const int qtok = g0 + (qr < 195 ? qr : 195);
    const half8 bq0 = *(const half8*)(Qp + ((size_t)quad * Nn + qtok) * 8);
    const half8 bq1 = *(const half8*)(Qp + ((size_t)(quad + 4) * Nn + qtok) * 8);

    f32x4 ex[13];
    float rs = 0.0f;
#pragma unroll
    for (int kt = 0; kt < 13; ++kt) {
      const int krr = kt * 16 + l15;
      const int ktok = g0 + (krr < 195 ? krr : 195);
      const half8 ak0 = *(const half8*)(Kp + ((size_t)quad * Nn + ktok) * 8);
      const half8 ak1 = *(const half8*)(Kp + ((size_t)(quad + 4) * Nn + ktok) * 8);
      f32x4 t = (f32x4)0.0f;
      t = MFMA(ak0, bq0, t);
      t = MFMA(ak1, bq1, t);
      f32x4 e;
#pragma unroll
      for (int r = 0; r < 4; ++r) e[r] = __expf(t[r]);
      if (kt == 12 && quad >= 1) e = (f32x4)0.0f;  // keys 196..207
      ex[kt] = e;
      rs += e[0] + e[1] + e[2] + e[3];
    }
#pragma unroll
    for (int kt = 0; kt < 13; ++kt)
#pragma unroll
      for (int r = 0; r < 4; ++r)
        Pw[l15 * 232 + kt * 16 + quad * 4 + r] = (_Float16)ex[kt][r];
    rs += __shfl_xor(rs, 16);
    rs += __shfl_xor(rs, 32);
    lds_fence();

    f32x4 acc[4];
#pragma unroll
    for (int mt = 0; mt < 4; ++mt) acc[mt] = (f32x4)0.0f;
#pragma unroll
    for (int c = 0; c < 7; ++c) {
      const half8 bp = *(const half8*)(Pw + l15 * 232 + c * 32 + quad * 8);
      const int k0 = c * 32 + quad * 8;
#pragma unroll
      for (int mt = 0; mt < 4; ++mt) {
        const int d = mt * 16 + l15;
        half8 av = h8z;
        if (k0 < 196) av = *(const half8*)(Vs + d * 216 + 8 + k0);
        acc[mt] = MFMA(av, bp, acc[mt]);  // O^T[d][q]
      }
    }
    const float inv = 1.0f / rs;
    if (qr < 196) {
      _Float16* base = Wbuf + (size_t)(b * Nn + g0 + qr) * Dd + h * HD;
#pragma unroll
      for (int mt = 0; mt < 4; ++mt) {
        half4h o;
#pragma unroll
        for (int r = 0; r < 4; ++r) o[r] = (_Float16)(acc[mt][r] * inv);
        *(half4h*)(base + mt * 16 + quad * 4) = o;
      }
    }
    __builtin_amdgcn_sched_barrier(0);
  }
}

// ----------------------------------------------------------- temporal attn
__global__ __launch_bounds__(256) void attn_temporal(const _Float16* __restrict__ Q8,
                                                     const _Float16* __restrict__ K8,
                                                     const _Float16* __restrict__ V8,
                                                     _Float16* __restrict__ Wbuf) {
  __shared__ __align__(16) _Float16 Plds[4][16 * 40];
  const int tid = threadIdx.x;
  const int lane = tid & 63, wid = tid >> 6;
  const int l15 = lane & 15, quad = lane >> 4;
  const int p = blockIdx.x * 4 + wid;
  const int J0 = p << 4;
  const int b = J0 / 18816;  // H2*N
  const int rem = J0 % 18816;
  const int hh = rem / Nn;
  const int n0 = rem % Nn;   // 16-aligned
  const size_t bh = (size_t)b * Hh + 6 + hh;
  const _Float16* Qp = Q8 + bh * 8 * (size_t)Nn * 8;
  const _Float16* Kp = K8 + bh * 8 * (size_t)Nn * 8;
  _Float16* Pw = &Plds[wid][0];

  const int tok = n0 + l15;
  const half8 bq0 = *(const half8*)(Qp + ((size_t)quad * Nn + tok) * 8);
  const half8 bq1 = *(const half8*)(Qp + ((size_t)(quad + 4) * Nn + tok) * 8);
  const half8 ak0 = *(const half8*)(Kp + ((size_t)quad * Nn + tok) * 8);
  const half8 ak1 = *(const half8*)(Kp + ((size_t)(quad + 4) * Nn + tok) * 8);
  f32x4 t = (f32x4)0.0f;
  t = MFMA(ak0, bq0, t);  // St[k][q]
  t = MFMA(ak1, bq1, t);
  f32x4 e;
#pragma unroll
  for (int r = 0; r < 4; ++r) e[r] = __expf(t[r]);
  float rs = e[0] + e[1] + e[2] + e[3];
  rs += __shfl_xor(rs, 16);
  rs += __shfl_xor(rs, 32);

#pragma unroll
  for (int r = 0; r < 4; ++r) Pw[l15 * 40 + quad * 4 + r] = (_Float16)e[r];
  {
    half4h z4;
    z4.x = z4.y = z4.z = z4.w = (_Float16)0.0f;
    *(half4h*)(Pw + l15 * 40 + 16 + quad * 4) = z4;  // zero k=16..31
  }
  lds_fence();

  const half8 bp = *(const half8*)(Pw + l15 * 40 + quad * 8);
  half8 h8z;
#pragma unroll
  for (int z = 0; z < 8; ++z) h8z[z] = (_Float16)0.0f;

  const float inv = 1.0f / rs;
  _Float16* base = Wbuf + (size_t)(b * Nn + n0 + l15) * Dd + (6 + hh) * HD;
#pragma unroll
  for (int mt = 0; mt < 4; ++mt) {
    const int d = mt * 16 + l15;
    half8 av = h8z;
    if (quad < 2)
      av = *(const half8*)(V8 + ((bh * NC + (n0 >> 3) + quad) * 64 + d) * 8);
    f32x4 acc = (f32x4)0.0f;
    acc = MFMA(av, bp, acc);  // O^T[d][q]
    half4h o;
#pragma unroll
    for (int r = 0; r < 4; ++r) o[r] = (_Float16)(acc[r] * inv);
    *(half4h*)(base + mt * 16 + quad * 4) = o;
  }
}

// ---------------------------------------------------------------- launcher
extern "C" void kernel_launch(void* const* d_in, const int* in_sizes, int n_in,
                              void* d_out, int out_size, void* d_ws, size_t ws_size,
                              hipStream_t stream) {
  const float* x = (const float*)d_in[0];
  const float* w_qkv = (const float*)d_in[1];
  const float* w_proj = (const float*)d_in[2];
  const float* b_proj = (const float*)d_in[3];
  float* out = (float*)d_out;

  _Float16* Xh = (_Float16*)d_ws;    // 19267584 elems; reused as Wbuf
  _Float16* Q8 = Xh + 19267584;      // (b,h,dc,n,8), pre-scaled by 0.125
  _Float16* K8 = Q8 + 19267584;
  _Float16* V8 = K8 + 19267584;      // (b,h,n/8,d,8)
  _Float16* Wqh = V8 + 19267584;     // 1769472
  _Float16* Wph = Wqh + 1769472;     // 589824

  cvt_all<<<21120, 256, 0, stream>>>(x, w_qkv, w_proj, Xh, Wqh, Wph);
  gemm_qkv<<<dim3(6, 196), 256, 0, stream>>>(Xh, Wqh,             Q8, K8, V8, 0);
  gemm_qkv<<<dim3(6, 196), 256, 0, stream>>>(Xh, Wqh + 768 * Dd,  Q8, K8, V8, 1);
  gemm_qkv<<<dim3(6, 196), 256, 0, stream>>>(Xh, Wqh + 1536 * Dd, Q8, K8, V8, 2);
  attn_spatial<<<768, 256, 0, stream>>>(Q8, K8, V8, Xh);
  attn_temporal<<<2352, 256, 0, stream>>>(Q8, K8, V8, Xh);
  gemm_proj<<<dim3(6, 196), 256, 0, stream>>>(Xh, Wph, b_proj, out);
}